// Round 1
// 2979.637 us; speedup vs baseline: 1.1277x; 1.1277x over previous
//
#include <hip/hip_runtime.h>
#include <cstdint>

typedef _Float16 half_t;
typedef __attribute__((ext_vector_type(2))) _Float16 half2_t;
typedef __attribute__((ext_vector_type(4))) _Float16 half4_t;
typedef __attribute__((ext_vector_type(8))) _Float16 half8_t;
typedef __attribute__((ext_vector_type(4))) float f32x4;

#define B_    32
#define DIN   128
#define LEN   2048
#define DS    512
#define NKT   16                            // K-tiles of 32 (16x16x32 MFMA)
#define KTR   12                            // K-tiles resident in registers/AGPRs
#define KTL   (NKT - KTR)                   // K-tiles streamed from LDS
#define LDSB_BYTES (KTL * 32 * 1024)        // 4 kt x 32 ntiles x 1KB = 131072
#define HBUF_OFF   LDSB_BYTES
#define LDS_BYTES  (LDSB_BYTES + 2 * DS * 2)   // + h ping-pong = 133120 < 160K

__device__ __forceinline__ float fast_tanh(float x) {
    float e = __expf(2.0f * x);        // large |x| saturates correctly via inf/0
    return 1.0f - 2.0f / (e + 1.0f);
}

__device__ __forceinline__ float fd2(uint32_t a, uint32_t b, float c) {
    return __builtin_amdgcn_fdot2(__builtin_bit_cast(half2_t, a),
                                  __builtin_bit_cast(half2_t, b), c, false);
}

// B-fragment for 16x16x32: lane(c=lane&15, q=lane>>4) holds B[k0+q*8+j][n0+c]
// = W[n0+c][k0+q*8+j], j=0..7 -> 8 consecutive f32 from W row n0+c.
__device__ __forceinline__ half8_t load_wfrag(const float* __restrict__ W,
                                              int n0, int c, int q, int kt) {
    const float* p = W + (size_t)(n0 + c) * DS + kt * 32 + q * 8;
    float4 f0 = *(const float4*)p;
    float4 f1 = *(const float4*)(p + 4);
    half8_t r = {(half_t)f0.x, (half_t)f0.y, (half_t)f0.z, (half_t)f0.w,
                 (half_t)f1.x, (half_t)f1.y, (half_t)f1.z, (half_t)f1.w};
    return r;
}

// ---------------------------------------------------------------- kernel A
// pre[b][l][h] = sum_d x[b][d][l]*W_ih[h][d] + b_ih[h] + b_hh[h]   (f16 out)
__global__ __launch_bounds__(256) void rnn_pre_kernel(
    const float* __restrict__ x, const float* __restrict__ Wih,
    const float* __restrict__ bih, const float* __restrict__ bhh,
    half_t* __restrict__ pre)
{
    __shared__ half_t Xs[64 * 136];    // [l][d], stride 136
    __shared__ half_t Ws[128 * 136];   // [h][d], stride 136
    const int t  = threadIdx.x;
    const int l0 = blockIdx.x * 64;
    const int b  = blockIdx.y;
    const int h0 = blockIdx.z * 128;

#pragma unroll
    for (int i = 0; i < 32; ++i) {
        int idx = i * 256 + t;
        int j = idx & 63, d = idx >> 6;
        Xs[j * 136 + d] = (half_t)x[(size_t)b * DIN * LEN + (size_t)d * LEN + l0 + j];
    }
#pragma unroll
    for (int i = 0; i < 16; ++i) {
        int f4 = i * 256 + t;
        int h = f4 >> 5, d4 = f4 & 31;
        float4 w = *(const float4*)&Wih[(size_t)(h0 + h) * DIN + d4 * 4];
        half4_t hw = {(half_t)w.x, (half_t)w.y, (half_t)w.z, (half_t)w.w};
        *(half4_t*)&Ws[h * 136 + d4 * 4] = hw;
    }
    __syncthreads();

    const int lb = (t >> 4) * 4;
    const int hb = (t & 15) * 8;
    float acc[4][8];
#pragma unroll
    for (int i = 0; i < 4; ++i)
#pragma unroll
        for (int j = 0; j < 8; ++j) acc[i][j] = 0.f;

    for (int kc = 0; kc < DIN; kc += 8) {
        uint4 xa[4], wb[8];
#pragma unroll
        for (int i = 0; i < 4; ++i) xa[i] = *(const uint4*)&Xs[(lb + i) * 136 + kc];
#pragma unroll
        for (int j = 0; j < 8; ++j) wb[j] = *(const uint4*)&Ws[(hb + j) * 136 + kc];
#pragma unroll
        for (int i = 0; i < 4; ++i)
#pragma unroll
            for (int j = 0; j < 8; ++j) {
                float a = acc[i][j];
                a = fd2(xa[i].x, wb[j].x, a);
                a = fd2(xa[i].y, wb[j].y, a);
                a = fd2(xa[i].z, wb[j].z, a);
                a = fd2(xa[i].w, wb[j].w, a);
                acc[i][j] = a;
            }
    }

    float bias[8];
#pragma unroll
    for (int j = 0; j < 8; ++j) bias[j] = bih[h0 + hb + j] + bhh[h0 + hb + j];
#pragma unroll
    for (int i = 0; i < 4; ++i) {
        half8_t s;
#pragma unroll
        for (int j = 0; j < 8; ++j) s[j] = (half_t)(acc[i][j] + bias[j]);
        *(half8_t*)&pre[((size_t)b * LEN + l0 + lb + i) * DS + h0 + hb] = s;
    }
}

// ---------------------------------------------------------------- kernel B
// MFMA scan: one block per batch. Wave w owns outputs n in [w*64, w*64+64)
// as 4 16-wide N-tiles. h_t replicated across M via A-operand (M=1 real).
// Since all 16 A-rows are identical, all 16 D-rows are identical: every lane
// (c,q) holds the result for column n0w + q*16 + c in acc[q].x -- which is
// exactly the column whose pre value this lane loaded. No shfl, no q==0
// divergence, 1 LDS write + 1 coalesced global store per lane.
// Barrier: s_waitcnt lgkmcnt(0) + s_barrier ONLY -- no vmcnt(0) drain, so the
// hs global stores and pre prefetch loads stay in flight across steps
// (nothing in this kernel reads hs; kernel C runs after kernel boundary).
__global__ __launch_bounds__(512) __attribute__((amdgpu_waves_per_eu(2, 2)))
void rnn_recur_kernel(
    const float* __restrict__ Whh, const half_t* __restrict__ pre,
    half_t* __restrict__ hs)
{
    extern __shared__ char smem[];
    const int t    = threadIdx.x;
    const int b    = blockIdx.x;
    const int w    = t >> 6;
    const int lane = t & 63;
    const int c    = lane & 15;
    const int q    = lane >> 4;
    const int n0w  = w * 64;

    // --- register-resident B-fragments (48 x half8 = 192 regs; MFMA-only use)
    half8_t breg[KTR][4];
#pragma unroll
    for (int kt = 0; kt < KTR; ++kt)
#pragma unroll
        for (int nt = 0; nt < 4; ++nt)
            breg[kt][nt] = load_wfrag(Whh, n0w + nt * 16, c, q, kt);

    // --- LDS-resident B-fragments, frag-linear: [(kt-KTR)*32+gid][lane*16B]
#pragma unroll
    for (int kt = KTR; kt < NKT; ++kt)
#pragma unroll
        for (int nt = 0; nt < 4; ++nt) {
            half8_t f = load_wfrag(Whh, n0w + nt * 16, c, q, kt);
            int gid = w * 4 + nt;
            *(half8_t*)(smem + (((kt - KTR) * 32 + gid) << 10) + lane * 16) = f;
        }
    if (t < DS) *(half_t*)(smem + HBUF_OFF + t * 2) = (half_t)0.f;  // h_{-1}=0
    __syncthreads();

    const half_t* prew = pre + (size_t)b * LEN * DS + n0w + lane;  // lane j -> n0w+j
    half_t* hsb = hs + (size_t)b * DS;
    float pv0 = (float)prew[0];            // pre value for this lane's column, step l
    float pv1 = (float)prew[DS];           // step l+1 (prefetch distance 2)

    int par = 0;
    for (int l = 0; l < LEN; ++l) {
        int l2 = (l + 2 < LEN) ? (l + 2) : (LEN - 1);
        float pv2 = (float)prew[(size_t)l2 * DS];                  // prefetch l+2

        const char* hb = smem + HBUF_OFF + par * 1024;
        f32x4 acc0 = {0.f, 0.f, 0.f, 0.f};
        f32x4 acc1 = {0.f, 0.f, 0.f, 0.f};
        f32x4 acc2 = {0.f, 0.f, 0.f, 0.f};
        f32x4 acc3 = {0.f, 0.f, 0.f, 0.f};
#pragma unroll
        for (int kt = 0; kt < KTR; ++kt) {
            half8_t a = *(const half8_t*)(hb + kt * 64 + q * 16);  // 4-addr multicast
            acc0 = __builtin_amdgcn_mfma_f32_16x16x32_f16(a, breg[kt][0], acc0, 0, 0, 0);
            acc1 = __builtin_amdgcn_mfma_f32_16x16x32_f16(a, breg[kt][1], acc1, 0, 0, 0);
            acc2 = __builtin_amdgcn_mfma_f32_16x16x32_f16(a, breg[kt][2], acc2, 0, 0, 0);
            acc3 = __builtin_amdgcn_mfma_f32_16x16x32_f16(a, breg[kt][3], acc3, 0, 0, 0);
        }
#pragma unroll
        for (int kt = KTR; kt < NKT; ++kt) {
            half8_t a = *(const half8_t*)(hb + kt * 64 + q * 16);
            const char* bb = smem + (((kt - KTR) * 32 + w * 4) << 10) + lane * 16;
            half8_t b0 = *(const half8_t*)(bb);
            half8_t b1 = *(const half8_t*)(bb + 1024);
            half8_t b2 = *(const half8_t*)(bb + 2048);
            half8_t b3 = *(const half8_t*)(bb + 3072);
            acc0 = __builtin_amdgcn_mfma_f32_16x16x32_f16(a, b0, acc0, 0, 0, 0);
            acc1 = __builtin_amdgcn_mfma_f32_16x16x32_f16(a, b1, acc1, 0, 0, 0);
            acc2 = __builtin_amdgcn_mfma_f32_16x16x32_f16(a, b2, acc2, 0, 0, 0);
            acc3 = __builtin_amdgcn_mfma_f32_16x16x32_f16(a, b3, acc3, 0, 0, 0);
        }

        // D rows all identical -> lane (c,q) has column n0w+q*16+c in acc[q].x,
        // matching this lane's own pv (prew + lane). Select acc by q (cndmask).
        float a01 = (q & 1) ? acc1.x : acc0.x;
        float a23 = (q & 1) ? acc3.x : acc2.x;
        float av  = (q & 2) ? a23 : a01;
        half_t hv = (half_t)fast_tanh(pv0 + av);

        char* hn = smem + HBUF_OFF + (par ^ 1) * 1024;
        *(half_t*)(hn + (n0w + lane) * 2) = hv;            // 128B/wave, conflict-free
        hsb[(size_t)l * (B_ * DS) + n0w + lane] = hv;      // coalesced 128B/wave

        pv0 = pv1;
        pv1 = pv2;
        par ^= 1;
        // LDS-only barrier: do NOT drain vmcnt (stores/prefetch stay in flight)
        asm volatile("s_waitcnt lgkmcnt(0)\n\ts_barrier" ::: "memory");
    }
}

// ---------------------------------------------------------------- kernel C
// y[r][o] = tanh(sum_s hs[r][s]*W_fc[o][s] + b_fc[o]),  r = l*B+b
__global__ __launch_bounds__(256) void rnn_out_kernel(
    const half_t* __restrict__ hs, const float* __restrict__ Wfc,
    const float* __restrict__ bfc, float* __restrict__ y)
{
    __shared__ half_t Hs[64 * 72];     // [r][k], stride 72
    __shared__ half_t Ws[128 * 72];    // [o][k], stride 72
    const int t  = threadIdx.x;
    const int r0 = blockIdx.x * 64;

    const int lb = (t >> 4) * 4;
    const int ob = (t & 15) * 8;
    float acc[4][8];
#pragma unroll
    for (int i = 0; i < 4; ++i)
#pragma unroll
        for (int j = 0; j < 8; ++j) acc[i][j] = 0.f;

    for (int kc = 0; kc < DS; kc += 64) {
#pragma unroll
        for (int i = 0; i < 2; ++i) {
            int u = i * 256 + t;
            int r = u >> 3, c8 = u & 7;
            uint4 v = ((const uint4*)(hs + (size_t)(r0 + r) * DS + kc))[c8];
            *(uint4*)&Hs[r * 72 + c8 * 8] = v;
        }
#pragma unroll
        for (int i = 0; i < 8; ++i) {
            int u = i * 256 + t;
            int o = u >> 4, c4 = u & 15;
            float4 wv = *(const float4*)&Wfc[(size_t)o * DS + kc + c4 * 4];
            half4_t hw = {(half_t)wv.x, (half_t)wv.y, (half_t)wv.z, (half_t)wv.w};
            *(half4_t*)&Ws[o * 72 + c4 * 4] = hw;
        }
        __syncthreads();
#pragma unroll
        for (int k8 = 0; k8 < 64; k8 += 8) {
            uint4 xa[4], wb[8];
#pragma unroll
            for (int i = 0; i < 4; ++i) xa[i] = *(const uint4*)&Hs[(lb + i) * 72 + k8];
#pragma unroll
            for (int j = 0; j < 8; ++j) wb[j] = *(const uint4*)&Ws[(ob + j) * 72 + k8];
#pragma unroll
            for (int i = 0; i < 4; ++i)
#pragma unroll
                for (int j = 0; j < 8; ++j) {
                    float a = acc[i][j];
                    a = fd2(xa[i].x, wb[j].x, a);
                    a = fd2(xa[i].y, wb[j].y, a);
                    a = fd2(xa[i].z, wb[j].z, a);
                    a = fd2(xa[i].w, wb[j].w, a);
                    acc[i][j] = a;
                }
        }
        __syncthreads();
    }

#pragma unroll
    for (int i = 0; i < 4; ++i) {
        float4 r0v = {fast_tanh(acc[i][0] + bfc[ob + 0]), fast_tanh(acc[i][1] + bfc[ob + 1]),
                      fast_tanh(acc[i][2] + bfc[ob + 2]), fast_tanh(acc[i][3] + bfc[ob + 3])};
        float4 r1v = {fast_tanh(acc[i][4] + bfc[ob + 4]), fast_tanh(acc[i][5] + bfc[ob + 5]),
                      fast_tanh(acc[i][6] + bfc[ob + 6]), fast_tanh(acc[i][7] + bfc[ob + 7])};
        float* yr = y + (size_t)(r0 + lb + i) * DIN + ob;
        *(float4*)yr       = r0v;
        *((float4*)yr + 1) = r1v;
    }
}

// ---------------------------------------------------------------- launch
extern "C" void kernel_launch(void* const* d_in, const int* in_sizes, int n_in,
                              void* d_out, int out_size, void* d_ws, size_t ws_size,
                              hipStream_t stream) {
    (void)in_sizes; (void)n_in; (void)out_size; (void)ws_size;
    const float* x   = (const float*)d_in[0];
    const float* Wih = (const float*)d_in[1];
    const float* Whh = (const float*)d_in[2];
    const float* bih = (const float*)d_in[3];
    const float* bhh = (const float*)d_in[4];
    const float* Wfc = (const float*)d_in[5];
    const float* bfc = (const float*)d_in[6];
    float* y = (float*)d_out;

    half_t* pre = (half_t*)d_ws;                                        // pre[b][l][h]: 64 MB
    half_t* hs  = (half_t*)((char*)d_ws + (size_t)B_ * LEN * DS * 2);   // hs[(l*B+b)][s]: 64 MB

    hipFuncSetAttribute((const void*)rnn_recur_kernel,
                        hipFuncAttributeMaxDynamicSharedMemorySize, LDS_BYTES);

    rnn_pre_kernel<<<dim3(LEN / 64, B_, DS / 128), 256, 0, stream>>>(x, Wih, bih, bhh, pre);
    rnn_recur_kernel<<<dim3(B_), 512, LDS_BYTES, stream>>>(Whh, pre, hs);
    rnn_out_kernel<<<dim3(LEN * B_ / 64), 256, 0, stream>>>(hs, Wfc, bfc, y);
}